// Round 1
// baseline (84.472 us; speedup 1.0000x reference)
//
#include <hip/hip_runtime.h>

#define NUM_CLASSES 4096
#define EMB_DIM 512

// Kernel 1: Wt[c][e] = W[e][c] + b[e]   (transpose + fused bias)
// W: [EMB_DIM][NUM_CLASSES] row-major, Wt: [NUM_CLASSES][EMB_DIM] row-major.
// 64x64 tiles staged through LDS so both the read and the write are coalesced.
__global__ void __launch_bounds__(1024)
transpose_bias_kernel(const float* __restrict__ W,
                      const float* __restrict__ b,
                      float* __restrict__ Wt) {
    __shared__ float tile[64][65];   // +1 pad: conflict-free transposed read
    const int c0 = blockIdx.x * 64;  // class-dim tile origin
    const int e0 = blockIdx.y * 64;  // emb-dim tile origin
    const int tx = threadIdx.x;      // 0..63
    const int ty = threadIdx.y;      // 0..15

    // Coalesced read: consecutive tx -> consecutive classes within a W row.
#pragma unroll
    for (int j = 0; j < 64; j += 16) {
        tile[ty + j][tx] = W[(size_t)(e0 + ty + j) * NUM_CLASSES + (c0 + tx)];
    }
    __syncthreads();

    const float bias = b[e0 + tx];
    // Coalesced write: consecutive tx -> consecutive emb elems within a Wt row.
#pragma unroll
    for (int j = 0; j < 64; j += 16) {
        Wt[(size_t)(c0 + ty + j) * EMB_DIM + (e0 + tx)] = tile[tx][ty + j] + bias;
    }
}

// Kernel 2: out[t][e] = Wt[x[t]][e], vectorized as float4 (16 B/lane).
// 128 consecutive threads handle one token's 512 floats -> contiguous 2 KiB
// read from Wt (L2/L3-hot) and contiguous 2 KiB write to out.
__global__ void __launch_bounds__(256)
gather_kernel(const int* __restrict__ x,
              const float4* __restrict__ Wt4,
              float4* __restrict__ out4,
              long long total4) {
    const long long stride = (long long)gridDim.x * blockDim.x;
    for (long long g = (long long)blockIdx.x * blockDim.x + threadIdx.x;
         g < total4; g += stride) {
        const int tok = (int)(g >> 7);   // / (EMB_DIM/4 = 128)
        const int e4  = (int)(g & 127);
        const int c   = x[tok];
        out4[g] = Wt4[(size_t)c * (EMB_DIM / 4) + e4];
    }
}

// Fallback (only if ws too small): direct strided gather, still correct.
__global__ void __launch_bounds__(256)
direct_kernel(const int* __restrict__ x,
              const float* __restrict__ W,
              const float* __restrict__ b,
              float* __restrict__ out,
              long long total) {
    const long long stride = (long long)gridDim.x * blockDim.x;
    for (long long g = (long long)blockIdx.x * blockDim.x + threadIdx.x;
         g < total; g += stride) {
        const int tok = (int)(g >> 9);   // / EMB_DIM
        const int e   = (int)(g & (EMB_DIM - 1));
        out[g] = W[(size_t)e * NUM_CLASSES + x[tok]] + b[e];
    }
}

extern "C" void kernel_launch(void* const* d_in, const int* in_sizes, int n_in,
                              void* d_out, int out_size, void* d_ws, size_t ws_size,
                              hipStream_t stream) {
    const int*   x = (const int*)d_in[0];    // [16, 8192] class ids
    const float* W = (const float*)d_in[1];  // [512, 4096]
    const float* b = (const float*)d_in[2];  // [512]
    float* out = (float*)d_out;              // [16, 8192, 512] f32

    const long long total = (long long)out_size;           // 67,108,864
    const size_t wt_bytes = (size_t)NUM_CLASSES * EMB_DIM * sizeof(float); // 8 MiB

    if (ws_size >= wt_bytes) {
        float* Wt = (float*)d_ws;
        dim3 tb(64, 16);
        dim3 tg(NUM_CLASSES / 64, EMB_DIM / 64);  // 64 x 8 = 512 blocks
        transpose_bias_kernel<<<tg, tb, 0, stream>>>(W, b, Wt);

        const long long total4 = total / 4;       // 16,777,216 float4
        gather_kernel<<<4096, 256, 0, stream>>>(x, (const float4*)Wt,
                                                (float4*)out, total4);
    } else {
        direct_kernel<<<4096, 256, 0, stream>>>(x, W, b, out, total);
    }
}

// Round 2
// 56.834 us; speedup vs baseline: 1.4863x; 1.4863x over previous
//
#include <hip/hip_runtime.h>

#define NUM_CLASSES 4096
#define EMB_DIM 512

typedef float f32x4 __attribute__((ext_vector_type(4)));

__device__ __forceinline__ unsigned int f2bf_rn(float f) {
    unsigned int u = __float_as_uint(f);
    u += 0x7fffu + ((u >> 16) & 1u);      // round-to-nearest-even
    return u >> 16;
}

// Kernel 1: Wtb[c][e] = bf16_rn(W[e][c] + b[e])
// W: [EMB_DIM][NUM_CLASSES] f32 row-major -> Wtb: [NUM_CLASSES][EMB_DIM] bf16.
// 4 MiB result == one XCD's L2, so the gather reads stay L2-resident.
__global__ void __launch_bounds__(1024)
transpose_bias_bf16_kernel(const float* __restrict__ W,
                           const float* __restrict__ b,
                           unsigned int* __restrict__ Wtb2) {  // 2 bf16 per uint
    __shared__ float tile[64][65];       // [e_local][c_local], +1 pad
    const int c0 = blockIdx.x * 64;
    const int e0 = blockIdx.y * 64;
    const int tx = threadIdx.x;          // 0..63
    const int ty = threadIdx.y;          // 0..15

    // Coalesced read: consecutive tx -> consecutive classes within a W row.
#pragma unroll
    for (int j = 0; j < 64; j += 16)
        tile[ty + j][tx] = W[(size_t)(e0 + ty + j) * NUM_CLASSES + (c0 + tx)];
    __syncthreads();

    // Write phase: thread t packs 2 consecutive e into one uint (coalesced).
    const int t  = ty * 64 + tx;         // 0..1023
    const int ep = t & 31;               // e-pair index 0..31
    const int r0 = t >> 5;               // class row 0..31
#pragma unroll
    for (int p = 0; p < 2; ++p) {
        const int r = r0 + p * 32;
        const int e = 2 * ep;
        // banks: (2*ep + r) % 32 -> 2-way aliasing (free per m136)
        const float v0 = tile[e][r]     + b[e0 + e];
        const float v1 = tile[e + 1][r] + b[e0 + e + 1];
        const unsigned int packed = f2bf_rn(v0) | (f2bf_rn(v1) << 16);
        Wtb2[((size_t)(c0 + r) * EMB_DIM + e0 + e) >> 1] = packed;
    }
}

// Kernel 2: out[t][e] = f32(Wtb[x[t]][e]), 4 f32 (one float4) per lane-iter.
// Reads 8 B/lane from the L2-hot bf16 table, nontemporal-stores 16 B/lane.
__global__ void __launch_bounds__(256)
gather_bf16_kernel(const int* __restrict__ x,
                   const uint2* __restrict__ Wtb4,   // 4 bf16 per uint2
                   f32x4* __restrict__ out4,
                   long long total4) {
    const long long stride = (long long)gridDim.x * (blockDim.x * 4);
    for (long long base = (long long)blockIdx.x * (blockDim.x * 4) + threadIdx.x;
         base < total4; base += stride) {
#pragma unroll
        for (int k = 0; k < 4; ++k) {
            const long long g = base + k * 256;
            if (g < total4) {
                const int c = x[g >> 7];                 // token's class id
                const uint2 raw = Wtb4[((size_t)c << 7) | (g & 127)];
                f32x4 v;
                v.x = __uint_as_float(raw.x << 16);
                v.y = __uint_as_float(raw.x & 0xffff0000u);
                v.z = __uint_as_float(raw.y << 16);
                v.w = __uint_as_float(raw.y & 0xffff0000u);
                __builtin_nontemporal_store(v, &out4[g]);
            }
        }
    }
}

// Fallback (only if ws too small): direct strided gather, still correct.
__global__ void __launch_bounds__(256)
direct_kernel(const int* __restrict__ x,
              const float* __restrict__ W,
              const float* __restrict__ b,
              float* __restrict__ out,
              long long total) {
    const long long stride = (long long)gridDim.x * blockDim.x;
    for (long long g = (long long)blockIdx.x * blockDim.x + threadIdx.x;
         g < total; g += stride) {
        const int tok = (int)(g >> 9);
        const int e   = (int)(g & (EMB_DIM - 1));
        out[g] = W[(size_t)e * NUM_CLASSES + x[tok]] + b[e];
    }
}

extern "C" void kernel_launch(void* const* d_in, const int* in_sizes, int n_in,
                              void* d_out, int out_size, void* d_ws, size_t ws_size,
                              hipStream_t stream) {
    const int*   x = (const int*)d_in[0];    // [16, 8192] class ids
    const float* W = (const float*)d_in[1];  // [512, 4096]
    const float* b = (const float*)d_in[2];  // [512]

    const long long total  = (long long)out_size;   // 67,108,864
    const long long total4 = total / 4;             // 16,777,216 float4
    const size_t wtb_bytes = (size_t)NUM_CLASSES * EMB_DIM * 2;  // 4 MiB bf16

    if (ws_size >= wtb_bytes) {
        unsigned int* Wtb = (unsigned int*)d_ws;
        dim3 tb(64, 16);
        dim3 tg(NUM_CLASSES / 64, EMB_DIM / 64);    // 64 x 8 blocks
        transpose_bias_bf16_kernel<<<tg, tb, 0, stream>>>(W, b, Wtb);

        const int blocks = (int)((total4 + 1023) >> 10);  // 4 float4/thread
        gather_bf16_kernel<<<blocks, 256, 0, stream>>>(
            x, (const uint2*)Wtb, (f32x4*)d_out, total4);
    } else {
        direct_kernel<<<4096, 256, 0, stream>>>(x, W, b, (float*)d_out, total);
    }
}

// Round 3
// 55.957 us; speedup vs baseline: 1.5096x; 1.0157x over previous
//
#include <hip/hip_runtime.h>

#define NUM_CLASSES 4096
#define EMB_DIM 512

typedef float f32x4 __attribute__((ext_vector_type(4)));

__device__ __forceinline__ unsigned int f2bf_rn(float f) {
    unsigned int u = __float_as_uint(f);
    u += 0x7fffu + ((u >> 16) & 1u);      // round-to-nearest-even
    return u >> 16;
}

// Kernel 1: Wtb[c][e] = bf16_rn(W[e][c] + b[e])
// W: [EMB_DIM][NUM_CLASSES] f32 row-major -> Wtb: [NUM_CLASSES][EMB_DIM] bf16.
// 4 MiB result == one XCD's L2, so the gather reads stay L2-resident.
__global__ void __launch_bounds__(1024)
transpose_bias_bf16_kernel(const float* __restrict__ W,
                           const float* __restrict__ b,
                           unsigned int* __restrict__ Wtb2) {  // 2 bf16 per uint
    __shared__ float tile[64][65];       // [e_local][c_local], +1 pad
    const int c0 = blockIdx.x * 64;
    const int e0 = blockIdx.y * 64;
    const int tx = threadIdx.x;          // 0..63
    const int ty = threadIdx.y;          // 0..15

#pragma unroll
    for (int j = 0; j < 64; j += 16)
        tile[ty + j][tx] = W[(size_t)(e0 + ty + j) * NUM_CLASSES + (c0 + tx)];
    __syncthreads();

    const int t  = ty * 64 + tx;         // 0..1023
    const int ep = t & 31;               // e-pair index 0..31
    const int r0 = t >> 5;               // class row 0..31
#pragma unroll
    for (int p = 0; p < 2; ++p) {
        const int r = r0 + p * 32;
        const int e = 2 * ep;
        const float v0 = tile[e][r]     + b[e0 + e];
        const float v1 = tile[e + 1][r] + b[e0 + e + 1];
        const unsigned int packed = f2bf_rn(v0) | (f2bf_rn(v1) << 16);
        Wtb2[((size_t)(c0 + r) * EMB_DIM + e0 + e) >> 1] = packed;
    }
}

// Kernel 2: out[t][e] = f32(Wtb[x[t]][e]).
// Each wave's 64 lanes cover exactly one token (64 consecutive float4 of a
// 128-float4 row; wave base is 64-aligned) -> token id is wave-uniform.
// readfirstlane forces the x[] load scalar (constant cache) and makes the
// table address SGPR-base + lane offset. Stores: unit-stride 16 B nt.
__global__ void __launch_bounds__(256)
gather_bf16_kernel(const int* __restrict__ x,
                   const uint2* __restrict__ Wtb4,   // 4 bf16 per uint2
                   f32x4* __restrict__ out4) {
    const int base = blockIdx.x * 1024 + threadIdx.x;   // float4 index, ILP=4
#pragma unroll
    for (int k = 0; k < 4; ++k) {
        const int g   = base + k * 256;
        const int tok = __builtin_amdgcn_readfirstlane(g >> 7);  // wave-uniform
        const int c   = x[tok];                                  // s_load
        const uint2 raw = Wtb4[(c << 7) | (g & 127)];
        f32x4 v;
        v.x = __uint_as_float(raw.x << 16);
        v.y = __uint_as_float(raw.x & 0xffff0000u);
        v.z = __uint_as_float(raw.y << 16);
        v.w = __uint_as_float(raw.y & 0xffff0000u);
        __builtin_nontemporal_store(v, &out4[g]);
    }
}

// Fallback (only if ws too small): direct strided gather, still correct.
__global__ void __launch_bounds__(256)
direct_kernel(const int* __restrict__ x,
              const float* __restrict__ W,
              const float* __restrict__ b,
              float* __restrict__ out,
              long long total) {
    const long long stride = (long long)gridDim.x * blockDim.x;
    for (long long g = (long long)blockIdx.x * blockDim.x + threadIdx.x;
         g < total; g += stride) {
        const int tok = (int)(g >> 9);
        const int e   = (int)(g & (EMB_DIM - 1));
        out[g] = W[(size_t)e * NUM_CLASSES + x[tok]] + b[e];
    }
}

extern "C" void kernel_launch(void* const* d_in, const int* in_sizes, int n_in,
                              void* d_out, int out_size, void* d_ws, size_t ws_size,
                              hipStream_t stream) {
    const int*   x = (const int*)d_in[0];    // [16, 8192] class ids
    const float* W = (const float*)d_in[1];  // [512, 4096]
    const float* b = (const float*)d_in[2];  // [512]

    const long long total  = (long long)out_size;   // 67,108,864
    const size_t wtb_bytes = (size_t)NUM_CLASSES * EMB_DIM * 2;  // 4 MiB bf16

    if (ws_size >= wtb_bytes) {
        unsigned int* Wtb = (unsigned int*)d_ws;
        dim3 tb(64, 16);
        dim3 tg(NUM_CLASSES / 64, EMB_DIM / 64);    // 64 x 8 blocks
        transpose_bias_bf16_kernel<<<tg, tb, 0, stream>>>(W, b, Wtb);

        // total4 = 16,777,216 float4; 1024 float4/block -> exact 16384 blocks
        gather_bf16_kernel<<<16384, 256, 0, stream>>>(
            x, (const uint2*)Wtb, (f32x4*)d_out);
    } else {
        direct_kernel<<<4096, 256, 0, stream>>>(x, W, b, (float*)d_out, total);
    }
}